// Round 4
// baseline (587.761 us; speedup 1.0000x reference)
//
#include <hip/hip_runtime.h>
#include <hip/hip_bf16.h>
#include <math.h>

// Problem constants
#define B   64
#define C   1024
#define HH  16
#define DD  64
#define MM  2048
#define LL  2049   // M+1
#define SCALE 0.125f
#define NCHC 9     // ctx row chunks
#define CHC  228   // rows per ctx chunk (9*228 = 2052 >= 2049)
#define L2ROWS 256 // logits rows per block
#define L2CK 32    // floats per c-chunk in logits

// ---------------- generic split-K GEMM: out_partial[kc][64][1024] ----------------
__global__ __launch_bounds__(256) void k_gemm(
    const float* __restrict__ A, int a_row_stride, int a_bx_off,
    const float* __restrict__ W, float* __restrict__ P) {
  __shared__ __attribute__((aligned(16))) float a_s[64 * 132];
  __shared__ __attribute__((aligned(16))) float b_s[128 * 68];
  int t = threadIdx.x;
  int jt = blockIdx.x, kc = blockIdx.y;
  const float* Ab = A + (size_t)jt * a_bx_off;
  int k0 = kc * 128;
  for (int idx = t; idx < 2048; idx += 256) {
    int bb = idx >> 5, f4 = idx & 31;
    float4 v = *(const float4*)&Ab[(size_t)bb * a_row_stride + k0 + 4 * f4];
    *(float4*)&a_s[bb * 132 + 4 * f4] = v;
  }
  for (int idx = t; idx < 2048; idx += 256) {
    int kk = idx >> 4, f4 = idx & 15;
    float4 v = *(const float4*)&W[(size_t)(k0 + kk) * 1024 + jt * 64 + 4 * f4];
    *(float4*)&b_s[kk * 68 + 4 * f4] = v;
  }
  __syncthreads();
  int j0 = (t & 15) * 4, b0 = (t >> 4) * 4;
  float4 acc[4];
#pragma unroll
  for (int i = 0; i < 4; ++i) acc[i] = make_float4(0.f, 0.f, 0.f, 0.f);
  for (int k = 0; k < 128; k += 4) {
    float4 w0 = *(const float4*)&b_s[(k + 0) * 68 + j0];
    float4 w1 = *(const float4*)&b_s[(k + 1) * 68 + j0];
    float4 w2 = *(const float4*)&b_s[(k + 2) * 68 + j0];
    float4 w3 = *(const float4*)&b_s[(k + 3) * 68 + j0];
#pragma unroll
    for (int i = 0; i < 4; ++i) {
      float4 av = *(const float4*)&a_s[(b0 + i) * 132 + k];
      acc[i].x += av.x * w0.x + av.y * w1.x + av.z * w2.x + av.w * w3.x;
      acc[i].y += av.x * w0.y + av.y * w1.y + av.z * w2.y + av.w * w3.y;
      acc[i].z += av.x * w0.z + av.y * w1.z + av.z * w2.z + av.w * w3.z;
      acc[i].w += av.x * w0.w + av.y * w1.w + av.z * w2.w + av.w * w3.w;
    }
  }
  size_t ob = (size_t)kc * 65536 + jt * 64;
#pragma unroll
  for (int i = 0; i < 4; ++i)
    *(float4*)&P[ob + (size_t)(b0 + i) * 1024 + j0] = acc[i];
}

__global__ __launch_bounds__(256) void k_reduce_qp(
    const float* __restrict__ P, const float* __restrict__ bq,
    const float* __restrict__ u, const float* __restrict__ v,
    float* __restrict__ qu, float* __restrict__ qv) {
  int idx = blockIdx.x * 256 + threadIdx.x;
  int b = idx >> 8, f4 = idx & 255;
  size_t off = (size_t)b * 1024 + 4 * f4;
  float4 s = *(const float4*)&P[off];
#pragma unroll
  for (int kc = 1; kc < 8; ++kc) {
    float4 t4 = *(const float4*)&P[(size_t)kc * 65536 + off];
    s.x += t4.x; s.y += t4.y; s.z += t4.z; s.w += t4.w;
  }
  float4 bb = *(const float4*)&bq[4 * f4];
  s.x += bb.x; s.y += bb.y; s.z += bb.z; s.w += bb.w;
  float4 uu = *(const float4*)&u[4 * f4];
  float4 vv = *(const float4*)&v[4 * f4];
  float4 o1 = make_float4(s.x + uu.x, s.y + uu.y, s.z + uu.z, s.w + uu.w);
  float4 o2 = make_float4(s.x + vv.x, s.y + vv.y, s.z + vv.z, s.w + vv.w);
  *(float4*)&qu[off] = o1;
  *(float4*)&qv[off] = o2;
}

__global__ __launch_bounds__(256) void k_reduce1(
    const float* __restrict__ P, const float* __restrict__ bias,
    float* __restrict__ out) {
  int idx = blockIdx.x * 256 + threadIdx.x;
  int b = idx >> 8, f4 = idx & 255;
  size_t off = (size_t)b * 1024 + 4 * f4;
  float4 s = *(const float4*)&P[off];
#pragma unroll
  for (int kc = 1; kc < 8; ++kc) {
    float4 t4 = *(const float4*)&P[(size_t)kc * 65536 + off];
    s.x += t4.x; s.y += t4.y; s.z += t4.z; s.w += t4.w;
  }
  float4 bb = *(const float4*)&bias[4 * f4];
  s.x += bb.x; s.y += bb.y; s.z += bb.z; s.w += bb.w;
  *(float4*)&out[off] = s;
}

// ---------------- wtilde: per-h GEMM ----------------
__global__ __launch_bounds__(256) void k_wtilde(
    const float* __restrict__ qu, const float* __restrict__ Wk,
    float* __restrict__ wt) {
  __shared__ __attribute__((aligned(16))) float a_s[64 * 68];
  __shared__ __attribute__((aligned(16))) float w_s[64 * 68];
  int t = threadIdx.x, ct = blockIdx.x, h = blockIdx.y;
  for (int idx = t; idx < 1024; idx += 256) {
    int bb = idx >> 4, f4 = idx & 15;
    *(float4*)&a_s[bb * 68 + 4 * f4] =
        *(const float4*)&qu[(size_t)bb * 1024 + h * 64 + 4 * f4];
  }
  for (int idx = t; idx < 1024; idx += 256) {
    int cc = idx >> 4, f4 = idx & 15;
    *(float4*)&w_s[cc * 68 + 4 * f4] =
        *(const float4*)&Wk[(size_t)(ct * 64 + cc) * 1024 + h * 64 + 4 * f4];
  }
  __syncthreads();
  int c0 = (t & 15) * 4, b0 = (t >> 4) * 4;
  float acc[4][4] = {};
  for (int d = 0; d < 64; d += 4) {
    float4 w0 = *(const float4*)&w_s[(c0 + 0) * 68 + d];
    float4 w1 = *(const float4*)&w_s[(c0 + 1) * 68 + d];
    float4 w2 = *(const float4*)&w_s[(c0 + 2) * 68 + d];
    float4 w3 = *(const float4*)&w_s[(c0 + 3) * 68 + d];
#pragma unroll
    for (int i = 0; i < 4; ++i) {
      float4 av = *(const float4*)&a_s[(b0 + i) * 68 + d];
      acc[i][0] += av.x * w0.x + av.y * w0.y + av.z * w0.z + av.w * w0.w;
      acc[i][1] += av.x * w1.x + av.y * w1.y + av.z * w1.z + av.w * w1.w;
      acc[i][2] += av.x * w2.x + av.y * w2.y + av.z * w2.z + av.w * w2.w;
      acc[i][3] += av.x * w3.x + av.y * w3.y + av.z * w3.z + av.w * w3.w;
    }
  }
#pragma unroll
  for (int i = 0; i < 4; ++i) {
    float4 o = make_float4(acc[i][0], acc[i][1], acc[i][2], acc[i][3]);
    *(float4*)&wt[(size_t)((b0 + i) * 16 + h) * 1024 + ct * 64 + c0] = o;
  }
}

// ---------------- sinusoidal table, reversed ----------------
__global__ void k_rtab(float* __restrict__ rtab) {
  int idx = blockIdx.x * 256 + threadIdx.x;
  if (idx >= LL * 64) return;
  int l = idx >> 6, d = idx & 63;
  float p = (float)(LL - 1 - l);
  int dd = d & 31;
  float f = 1.0f / powf(10000.0f, (float)dd * (1.0f / 32.0f));
  float a = p * f;
  rtab[idx] = (d < 32) ? sinf(a) : cosf(a);
}

// ---------------- logits: row-per-lane, no cross-lane reduce ----------------
// grid (9, 64): lane t owns row l0+t. cat staged to LDS coalesced (XOR-swizzled);
// wt read via wave-uniform s_load; bd term computed inline at block end.
__global__ __launch_bounds__(256) void k_logits2(
    const float* __restrict__ x, const float* __restrict__ mem,
    const float* __restrict__ wt, const float* __restrict__ qv,
    const float* __restrict__ rtab, float* __restrict__ logits) {
  __shared__ __attribute__((aligned(16))) float cat_s[L2ROWS * 36];
  int t = threadIdx.x;
  int b = blockIdx.y, ch = blockIdx.x;
  int l0 = ch * L2ROWS;
  int myl = l0 + t;
  int lcl = min(myl, LL - 1);  // clamp: duplicate last row, write-guarded
  const float* wtb = &wt[(size_t)b * 16384];
  float acc[16];
#pragma unroll
  for (int h = 0; h < 16; ++h) acc[h] = 0.f;
  int key = (t >> 3) & 7;

  for (int c0 = 0; c0 < 1024; c0 += L2CK) {
    // stage 256 rows x 32 c, coalesced global, swizzled LDS write
    for (int idx = t; idx < L2ROWS * 8; idx += 256) {
      int r = idx >> 3, c4 = idx & 7;
      int l = min(l0 + r, LL - 1);
      const float* src = (l < MM) ? &mem[((size_t)b * MM + l) * 1024]
                                  : &x[(size_t)b * 1024];
      float4 v = *(const float4*)&src[c0 + 4 * c4];
      int sw = c4 ^ ((r >> 3) & 7);
      *(float4*)&cat_s[r * 36 + 4 * sw] = v;
    }
    __syncthreads();
    float4 cv[8];
#pragma unroll
    for (int k = 0; k < 8; ++k)
      cv[k] = *(const float4*)&cat_s[t * 36 + 4 * (k ^ key)];
#pragma unroll 2
    for (int h = 0; h < 16; ++h) {
      const float4* wp = (const float4*)&wtb[h * 1024 + c0];  // uniform -> s_load
      float s = 0.f;
#pragma unroll
      for (int k = 0; k < 8; ++k) {
        float4 wv = wp[k];
        s += cv[k].x * wv.x + cv[k].y * wv.y + cv[k].z * wv.z + cv[k].w * wv.w;
      }
      acc[h] += s;
    }
    __syncthreads();
  }
  // bd term: qv[b,h,:] . rtab[l,:], qv uniform (s_load), rtab lane-private (L2-hot)
  float4 rv[16];
#pragma unroll
  for (int k = 0; k < 16; ++k)
    rv[k] = *(const float4*)&rtab[(size_t)lcl * 64 + 4 * k];
#pragma unroll 2
  for (int h = 0; h < 16; ++h) {
    const float4* qp = (const float4*)&qv[(size_t)b * 1024 + h * 64];  // uniform
    float s = 0.f;
#pragma unroll
    for (int k = 0; k < 16; ++k) {
      float4 q = qp[k];
      s += rv[k].x * q.x + rv[k].y * q.y + rv[k].z * q.z + rv[k].w * q.w;
    }
    if (myl < LL)
      logits[(size_t)(b * 16 + h) * LL + myl] = (acc[h] + s) * SCALE;
  }
}

// ---------------- softmax over l, in place. grid 1024 (b*16+h) ----------------
__global__ __launch_bounds__(256) void k_softmax(float* __restrict__ logits) {
  __shared__ float red[8];
  int t = threadIdx.x;
  size_t base = (size_t)blockIdx.x * LL;
  float rv[9];
  float m = -1e30f;
#pragma unroll
  for (int k = 0; k < 9; ++k) {
    int i = t + k * 256;
    rv[k] = (i < LL) ? logits[base + i] : -1e30f;
    m = fmaxf(m, rv[k]);
  }
#pragma unroll
  for (int s = 1; s < 64; s <<= 1) m = fmaxf(m, __shfl_xor(m, s, 64));
  if ((t & 63) == 0) red[t >> 6] = m;
  __syncthreads();
  m = fmaxf(fmaxf(red[0], red[1]), fmaxf(red[2], red[3]));
  float sum = 0.f;
#pragma unroll
  for (int k = 0; k < 9; ++k) {
    int i = t + k * 256;
    float e = __expf(rv[k] - m);
    rv[k] = e;
    if (i < LL) sum += e;
  }
#pragma unroll
  for (int s = 1; s < 64; s <<= 1) sum += __shfl_xor(sum, s, 64);
  if ((t & 63) == 0) red[4 + (t >> 6)] = sum;
  __syncthreads();
  float inv = 1.0f / (red[4] + red[5] + red[6] + red[7]);
#pragma unroll
  for (int k = 0; k < 9; ++k) {
    int i = t + k * 256;
    if (i < LL) logits[base + i] = rv[k] * inv;
  }
}

// ---------------- ctx pass: register-resident, global-direct ----------------
__global__ __launch_bounds__(256) void k_ctx(
    const float* __restrict__ x, const float* __restrict__ mem,
    const float* __restrict__ attn, float* __restrict__ part) {
  __shared__ __attribute__((aligned(16))) float att_s[CHC * 20];
  int t = threadIdx.x;
  int lane = t & 63, w = t >> 6;
  int b = blockIdx.y;
  int ch = blockIdx.x >> 2, cq = blockIdx.x & 3;
  int l0 = ch * CHC, lend = min(LL, l0 + CHC);
  int natt = lend - l0;
  int c_off = cq * 256 + lane * 4;
#pragma unroll
  for (int h = 0; h < 16; ++h)
    for (int r = t; r < natt; r += 256)
      att_s[r * 20 + h] = attn[(size_t)(b * 16 + h) * LL + l0 + r];
  __syncthreads();
  float4 acc[16];
#pragma unroll
  for (int i = 0; i < 16; ++i) acc[i] = make_float4(0.f, 0.f, 0.f, 0.f);
  const float* xrow = &x[(size_t)b * 1024 + c_off];
  const float* memb = &mem[(size_t)b * MM * 1024 + c_off];

  for (int g0 = l0 + w * 8; g0 < lend; g0 += 32) {
    int nr = min(8, lend - g0);
    float4 rb[8];
#pragma unroll
    for (int r = 0; r < 8; ++r) {
      int l = g0 + r;
      rb[r] = *(const float4*)((l < MM) ? &memb[(size_t)l * 1024] : xrow);
    }
#pragma unroll
    for (int r = 0; r < 8; ++r) {
      if (r < nr) {
        int ri = g0 + r - l0;
        const float4* a4 = (const float4*)&att_s[ri * 20];
        float4 aA = a4[0], aB = a4[1], aC = a4[2], aD = a4[3];
        float4 rv = rb[r];
#define ACC1(i, s)                                                       \
  acc[i].x += (s) * rv.x; acc[i].y += (s) * rv.y;                        \
  acc[i].z += (s) * rv.z; acc[i].w += (s) * rv.w;
        ACC1(0, aA.x) ACC1(1, aA.y) ACC1(2, aA.z) ACC1(3, aA.w)
        ACC1(4, aB.x) ACC1(5, aB.y) ACC1(6, aB.z) ACC1(7, aB.w)
        ACC1(8, aC.x) ACC1(9, aC.y) ACC1(10, aC.z) ACC1(11, aC.w)
        ACC1(12, aD.x) ACC1(13, aD.y) ACC1(14, aD.z) ACC1(15, aD.w)
#undef ACC1
      }
    }
  }
  __syncthreads();
  float* accb = att_s;
  for (int ww = 0; ww < 4; ++ww) {
    if (w == ww) {
      if (ww == 0) {
#pragma unroll
        for (int h = 0; h < 16; ++h)
          *(float4*)&accb[h * 256 + lane * 4] = acc[h];
      } else {
#pragma unroll
        for (int h = 0; h < 16; ++h) {
          float4 vv = *(const float4*)&accb[h * 256 + lane * 4];
          vv.x += acc[h].x; vv.y += acc[h].y;
          vv.z += acc[h].z; vv.w += acc[h].w;
          *(float4*)&accb[h * 256 + lane * 4] = vv;
        }
      }
    }
    __syncthreads();
  }
  size_t pb = (size_t)((b * NCHC + ch) * 16) * 1024 + cq * 256;
  for (int idx = t; idx < 1024; idx += 256) {
    int h = idx >> 6, c4 = idx & 63;
    *(float4*)&part[pb + (size_t)h * 1024 + 4 * c4] =
        *(const float4*)&accb[h * 256 + 4 * c4];
  }
}

// ---------------- sum 9 chunk partials -> ctx ----------------
__global__ __launch_bounds__(256) void k_ctxreduce(
    const float* __restrict__ part, float* __restrict__ ctx) {
  int o4 = blockIdx.x * 256 + threadIdx.x;
  size_t o = (size_t)o4 * 4;
  int b = (int)(o >> 14);
  int rem = (int)(o & 16383);
  const float* p = &part[(size_t)b * (NCHC * 16384) + rem];
  float4 s = *(const float4*)p;
#pragma unroll
  for (int chk = 1; chk < NCHC; ++chk) {
    float4 v = *(const float4*)&p[(size_t)chk * 16384];
    s.x += v.x; s.y += v.y; s.z += v.z; s.w += v.w;
  }
  *(float4*)&ctx[o] = s;
}

extern "C" void kernel_launch(void* const* d_in, const int* in_sizes, int n_in,
                              void* d_out, int out_size, void* d_ws,
                              size_t ws_size, hipStream_t stream) {
  const float* x = (const float*)d_in[0];
  const float* mem = (const float*)d_in[1];
  const float* Wq = (const float*)d_in[2];
  const float* bq = (const float*)d_in[3];
  const float* Wk = (const float*)d_in[4];
  // d_in[5] = bk : constant over l -> cancels in softmax, unused.
  const float* Wv = (const float*)d_in[6];
  const float* bv = (const float*)d_in[7];
  const float* u_bias = (const float*)d_in[8];
  const float* v_bias = (const float*)d_in[9];
  const float* Wo = (const float*)d_in[10];
  const float* bo = (const float*)d_in[11];
  float* out = (float*)d_out;

  float* ws = (float*)d_ws;
  // Region A (persistent): 3,343,360 floats
  float* qu = ws;                         // 65536
  float* qv = qu + 65536;                 // 65536
  float* logits = qv + 65536;             // 2098176
  float* ctx = logits + 2098176;          // 1048576
  float* out1 = ctx + 1048576;            // 65536
  // Region B (aliased): 9,437,184 floats (= part)
  float* Bb = out1 + 65536;
  float* wt = Bb;                         // 1048576 (dead after k_logits2)
  float* rtab = Bb + 1048576;             // 131200  (dead after k_logits2)
  float* P = Bb + 1179776;                // 524288  (early use + post-part use)
  float* part = Bb;                       // 9437184 (k_ctx..k_ctxreduce only)
  // total = 12,780,544 floats = 51.1 MB

  k_gemm<<<dim3(16, 8), 256, 0, stream>>>(x, 1024, 0, Wq, P);
  k_rtab<<<dim3(513), 256, 0, stream>>>(rtab);
  k_reduce_qp<<<dim3(64), 256, 0, stream>>>(P, bq, u_bias, v_bias, qu, qv);
  k_wtilde<<<dim3(16, 16), 256, 0, stream>>>(qu, Wk, wt);
  k_logits2<<<dim3(9, 64), 256, 0, stream>>>(x, mem, wt, qv, rtab, logits);
  k_softmax<<<dim3(1024), 256, 0, stream>>>(logits);
  k_ctx<<<dim3(36, 64), 256, 0, stream>>>(x, mem, logits, part);
  k_ctxreduce<<<dim3(1024), 256, 0, stream>>>(part, ctx);
  k_gemm<<<dim3(16, 8), 256, 0, stream>>>(ctx, 16384, 1024, Wv, P);
  k_reduce1<<<dim3(64), 256, 0, stream>>>(P, bv, out1);
  k_gemm<<<dim3(16, 8), 256, 0, stream>>>(out1, 1024, 0, Wo, P);
  k_reduce1<<<dim3(64), 256, 0, stream>>>(P, bo, out);
}